// Round 1
// baseline (941.687 us; speedup 1.0000x reference)
//
#include <hip/hip_runtime.h>
#include <math.h>

namespace {

constexpr int B = 4, N = 2048, DIM = 768, H = 12, CD = 64, M = 384;
constexpr float SCALE = 0.35355339059327379f;     // 64^-0.25
constexpr float INV_SQRT_M = 0.05103103630798288f; // 1/sqrt(384)
constexpr float EPS = 1e-8f;

// ---------------- generic 64x64 tiled SGEMM: C = A(MxK)@B(KxN) [+bias] ----------------
template <bool HAS_BIAS>
__global__ __launch_bounds__(256) void sgemm_k(const float* __restrict__ A,
                                               const float* __restrict__ Bm,
                                               const float* __restrict__ bias,
                                               float* __restrict__ Cm,
                                               int Mdim, int Ndim, int Kdim) {
  __shared__ float As[16][68];  // [k][m]
  __shared__ float Bs[16][68];  // [k][n]
  const int bm = blockIdx.y * 64;
  const int bn = blockIdx.x * 64;
  const int t = (int)threadIdx.x;
  const int tm = (t >> 4) * 4;
  const int tn = (t & 15) * 4;

  float bv[4] = {0.f, 0.f, 0.f, 0.f};
  if (HAS_BIAS) {
#pragma unroll
    for (int j = 0; j < 4; ++j) bv[j] = bias[bn + tn + j];
  }

  float acc[4][4] = {};

  const int am = t >> 2;       // A tile row 0..63
  const int ak = (t & 3) * 4;  // A tile k-quad
  const int bk = t >> 4;       // B tile row 0..15
  const int bnq = (t & 15) * 4;

  for (int k0 = 0; k0 < Kdim; k0 += 16) {
    const float4 a4 = *reinterpret_cast<const float4*>(&A[(size_t)(bm + am) * Kdim + k0 + ak]);
    const float4 b4 = *reinterpret_cast<const float4*>(&Bm[(size_t)(k0 + bk) * Ndim + bn + bnq]);
    As[ak + 0][am] = a4.x;
    As[ak + 1][am] = a4.y;
    As[ak + 2][am] = a4.z;
    As[ak + 3][am] = a4.w;
    *reinterpret_cast<float4*>(&Bs[bk][bnq]) = b4;
    __syncthreads();
#pragma unroll
    for (int k = 0; k < 16; ++k) {
      const float4 av = *reinterpret_cast<const float4*>(&As[k][tm]);
      const float4 bw = *reinterpret_cast<const float4*>(&Bs[k][tn]);
      const float aa[4] = {av.x, av.y, av.z, av.w};
      const float bb[4] = {bw.x, bw.y, bw.z, bw.w};
#pragma unroll
      for (int i = 0; i < 4; ++i)
#pragma unroll
        for (int j = 0; j < 4; ++j) acc[i][j] = fmaf(aa[i], bb[j], acc[i][j]);
    }
    __syncthreads();
  }

#pragma unroll
  for (int i = 0; i < 4; ++i) {
    float4 o;
    o.x = acc[i][0] + bv[0];
    o.y = acc[i][1] + bv[1];
    o.z = acc[i][2] + bv[2];
    o.w = acc[i][3] + bv[3];
    *reinterpret_cast<float4*>(&Cm[(size_t)(bm + tm + i) * Ndim + bn + tn]) = o;
  }
}

// ---------------- stage 2: phi(k), ksum, ktv per (m-block, h, b) ----------------
__global__ __launch_bounds__(256) void kv_stage_k(const float* __restrict__ qkv,
                                                  const float* __restrict__ w,
                                                  float* __restrict__ ktv,
                                                  float* __restrict__ ksum) {
  __shared__ float w_s[64][68];   // [c][m]
  __shared__ float kp_s[64][68];  // k tile [n][c], then phi [n][m]
  __shared__ float v_s[64][68];   // [n][c]
  __shared__ float sq_part[64][4];

  const int mb = blockIdx.x * 64;
  const int h = blockIdx.y;
  const int b = blockIdx.z;
  const int t = (int)threadIdx.x;
  const int tm = (t >> 4) * 4;
  const int tn = (t & 15) * 4;

  // load w tile once: w_s[c][m'] = w[h][c][mb+m']
  {
    const int r = t >> 4;
    const int cq = (t & 15) * 4;
#pragma unroll
    for (int i = 0; i < 4; ++i) {
      const int c = r + i * 16;
      *reinterpret_cast<float4*>(&w_s[c][cq]) =
          *reinterpret_cast<const float4*>(&w[((size_t)(h * 64 + c)) * M + mb + cq]);
    }
  }

  float acc[4][4] = {};            // ktv block: m=tm+i, c=tn+j
  float ksr[4] = {0.f, 0.f, 0.f, 0.f};

  for (int n0 = 0; n0 < N; n0 += 64) {
    __syncthreads();  // protects kp_s/v_s reuse; makes w_s visible on first iter
    {
      const int r = t >> 4;
      const int cq = (t & 15) * 4;
#pragma unroll
      for (int i = 0; i < 4; ++i) {
        const int n = r + i * 16;
        const size_t rowbase = ((size_t)(b * N + n0 + n)) * 2304 + (size_t)h * 64;
        *reinterpret_cast<float4*>(&kp_s[n][cq]) =
            *reinterpret_cast<const float4*>(&qkv[rowbase + 768 + cq]);
        *reinterpret_cast<float4*>(&v_s[n][cq]) =
            *reinterpret_cast<const float4*>(&qkv[rowbase + 1536 + cq]);
      }
    }
    __syncthreads();
    {  // sq partials: n = t>>2, 16 c's each
      const int n = t >> 2;
      const int c0 = (t & 3) * 16;
      float s = 0.f;
#pragma unroll
      for (int c = 0; c < 16; c += 4) {
        const float4 kk = *reinterpret_cast<const float4*>(&kp_s[n][c0 + c]);
        s = fmaf(kk.x, kk.x, s);
        s = fmaf(kk.y, kk.y, s);
        s = fmaf(kk.z, kk.z, s);
        s = fmaf(kk.w, kk.w, s);
      }
      sq_part[n][t & 3] = s;
    }
    __syncthreads();
    // GEMM1: proj[n=tm+i][m=tn+j] = sum_c k[n][c]*w[c][m]
    float ph[4][4] = {};
    for (int c = 0; c < 64; c += 4) {
      float4 a4[4], b4[4];
#pragma unroll
      for (int i = 0; i < 4; ++i) a4[i] = *reinterpret_cast<const float4*>(&kp_s[tm + i][c]);
#pragma unroll
      for (int cc = 0; cc < 4; ++cc) b4[cc] = *reinterpret_cast<const float4*>(&w_s[c + cc][tn]);
#pragma unroll
      for (int i = 0; i < 4; ++i) {
        const float av[4] = {a4[i].x, a4[i].y, a4[i].z, a4[i].w};
#pragma unroll
        for (int cc = 0; cc < 4; ++cc) {
          ph[i][0] = fmaf(av[cc], b4[cc].x, ph[i][0]);
          ph[i][1] = fmaf(av[cc], b4[cc].y, ph[i][1]);
          ph[i][2] = fmaf(av[cc], b4[cc].z, ph[i][2]);
          ph[i][3] = fmaf(av[cc], b4[cc].w, ph[i][3]);
        }
      }
    }
#pragma unroll
    for (int i = 0; i < 4; ++i) {
      const float4 sp = *reinterpret_cast<const float4*>(&sq_part[tm + i][0]);
      const float sq = 0.5f * SCALE * SCALE * (sp.x + sp.y + sp.z + sp.w);
#pragma unroll
      for (int j = 0; j < 4; ++j) ph[i][j] = __expf(fmaf(SCALE, ph[i][j], -sq)) * INV_SQRT_M;
    }
    __syncthreads();  // all done reading kp_s as K
#pragma unroll
    for (int i = 0; i < 4; ++i)
      *reinterpret_cast<float4*>(&kp_s[tm + i][tn]) =
          make_float4(ph[i][0], ph[i][1], ph[i][2], ph[i][3]);
    __syncthreads();
    // GEMM2: ktv[m=tm+i][c=tn+j] += sum_n phi[n][m]*v[n][c]; ksum[m] += phi[n][m]
    for (int n = 0; n < 64; ++n) {
      const float4 pa = *reinterpret_cast<const float4*>(&kp_s[n][tm]);
      const float4 vv = *reinterpret_cast<const float4*>(&v_s[n][tn]);
      const float av[4] = {pa.x, pa.y, pa.z, pa.w};
#pragma unroll
      for (int i = 0; i < 4; ++i) {
        acc[i][0] = fmaf(av[i], vv.x, acc[i][0]);
        acc[i][1] = fmaf(av[i], vv.y, acc[i][1]);
        acc[i][2] = fmaf(av[i], vv.z, acc[i][2]);
        acc[i][3] = fmaf(av[i], vv.w, acc[i][3]);
      }
      ksr[0] += av[0];
      ksr[1] += av[1];
      ksr[2] += av[2];
      ksr[3] += av[3];
    }
  }
  const size_t base = (size_t)(b * H + h) * M + mb;
#pragma unroll
  for (int i = 0; i < 4; ++i)
    *reinterpret_cast<float4*>(&ktv[(base + tm + i) * 64 + tn]) =
        make_float4(acc[i][0], acc[i][1], acc[i][2], acc[i][3]);
  if (tn == 0) {
#pragma unroll
    for (int i = 0; i < 4; ++i) ksum[base + tm + i] = ksr[i];
  }
}

// ---------------- stage 3: phi(q), D, out per (n-block, h, b) ----------------
__global__ __launch_bounds__(256) void q_stage_k(const float* __restrict__ qkv,
                                                 const float* __restrict__ w,
                                                 const float* __restrict__ ktv,
                                                 const float* __restrict__ ksum,
                                                 float* __restrict__ attn) {
  __shared__ float q_s[64][68];    // [n][c]
  __shared__ float w_s[64][36];    // [c][m'] (32 wide)
  __shared__ float ktv_s[32][68];  // [m'][c]
  __shared__ float phi_s[64][36];  // [n][m']
  __shared__ float sq_part[64][4];
  __shared__ float ksum_s[32];
  __shared__ float d_s[64];

  const int nb = blockIdx.x * 64;
  const int h = blockIdx.y;
  const int b = blockIdx.z;
  const int t = (int)threadIdx.x;
  const int tm = (t >> 4) * 4;  // n-quad (GEMM2/out)
  const int tn = (t & 15) * 4;  // c-quad

  {  // load q tile
    const int r = t >> 4;
    const int cq = (t & 15) * 4;
#pragma unroll
    for (int i = 0; i < 4; ++i) {
      const int n = r + i * 16;
      *reinterpret_cast<float4*>(&q_s[n][cq]) = *reinterpret_cast<const float4*>(
          &qkv[((size_t)(b * N + nb + n)) * 2304 + (size_t)h * 64 + cq]);
    }
  }
  __syncthreads();
  {  // sq partials
    const int n = t >> 2;
    const int c0 = (t & 3) * 16;
    float s = 0.f;
#pragma unroll
    for (int c = 0; c < 16; c += 4) {
      const float4 kk = *reinterpret_cast<const float4*>(&q_s[n][c0 + c]);
      s = fmaf(kk.x, kk.x, s);
      s = fmaf(kk.y, kk.y, s);
      s = fmaf(kk.z, kk.z, s);
      s = fmaf(kk.w, kk.w, s);
    }
    sq_part[n][t & 3] = s;
  }

  float oacc[4][4] = {};
  float dreg[4] = {0.f, 0.f, 0.f, 0.f};

  const int pn2 = (t >> 3) * 2;  // phi rows
  const int pm4 = (t & 7) * 4;   // phi cols

  for (int mb = 0; mb < M; mb += 32) {
    __syncthreads();  // protects w_s/ktv_s/phi_s; sq_part visible on first iter
    {
      const int c = t >> 2;
      const int mq = (t & 3) * 8;
#pragma unroll
      for (int j = 0; j < 2; ++j)
        *reinterpret_cast<float4*>(&w_s[c][mq + 4 * j]) = *reinterpret_cast<const float4*>(
            &w[((size_t)(h * 64 + c)) * M + mb + mq + 4 * j]);
    }
    {
      const int r = t >> 3;
      const int cq = (t & 7) * 8;
      const size_t kbase = ((size_t)(b * H + h) * M + mb + r) * 64;
#pragma unroll
      for (int j = 0; j < 2; ++j)
        *reinterpret_cast<float4*>(&ktv_s[r][cq + 4 * j]) =
            *reinterpret_cast<const float4*>(&ktv[kbase + cq + 4 * j]);
    }
    if (t < 32) ksum_s[t] = ksum[(size_t)(b * H + h) * M + mb + t];
    __syncthreads();
    // GEMM1: proj[n=pn2+i (2)][m=pm4+j (4)]
    float pacc[2][4] = {};
    for (int c = 0; c < 64; c += 4) {
      const float4 a0 = *reinterpret_cast<const float4*>(&q_s[pn2][c]);
      const float4 a1 = *reinterpret_cast<const float4*>(&q_s[pn2 + 1][c]);
      const float av0[4] = {a0.x, a0.y, a0.z, a0.w};
      const float av1[4] = {a1.x, a1.y, a1.z, a1.w};
#pragma unroll
      for (int cc = 0; cc < 4; ++cc) {
        const float4 b4 = *reinterpret_cast<const float4*>(&w_s[c + cc][pm4]);
        pacc[0][0] = fmaf(av0[cc], b4.x, pacc[0][0]);
        pacc[0][1] = fmaf(av0[cc], b4.y, pacc[0][1]);
        pacc[0][2] = fmaf(av0[cc], b4.z, pacc[0][2]);
        pacc[0][3] = fmaf(av0[cc], b4.w, pacc[0][3]);
        pacc[1][0] = fmaf(av1[cc], b4.x, pacc[1][0]);
        pacc[1][1] = fmaf(av1[cc], b4.y, pacc[1][1]);
        pacc[1][2] = fmaf(av1[cc], b4.z, pacc[1][2]);
        pacc[1][3] = fmaf(av1[cc], b4.w, pacc[1][3]);
      }
    }
    {
      const float4 sp0 = *reinterpret_cast<const float4*>(&sq_part[pn2][0]);
      const float4 sp1 = *reinterpret_cast<const float4*>(&sq_part[pn2 + 1][0]);
      const float sq0 = 0.5f * SCALE * SCALE * (sp0.x + sp0.y + sp0.z + sp0.w);
      const float sq1 = 0.5f * SCALE * SCALE * (sp1.x + sp1.y + sp1.z + sp1.w);
      float4 o0, o1;
      o0.x = __expf(fmaf(SCALE, pacc[0][0], -sq0)) * INV_SQRT_M;
      o0.y = __expf(fmaf(SCALE, pacc[0][1], -sq0)) * INV_SQRT_M;
      o0.z = __expf(fmaf(SCALE, pacc[0][2], -sq0)) * INV_SQRT_M;
      o0.w = __expf(fmaf(SCALE, pacc[0][3], -sq0)) * INV_SQRT_M;
      o1.x = __expf(fmaf(SCALE, pacc[1][0], -sq1)) * INV_SQRT_M;
      o1.y = __expf(fmaf(SCALE, pacc[1][1], -sq1)) * INV_SQRT_M;
      o1.z = __expf(fmaf(SCALE, pacc[1][2], -sq1)) * INV_SQRT_M;
      o1.w = __expf(fmaf(SCALE, pacc[1][3], -sq1)) * INV_SQRT_M;
      *reinterpret_cast<float4*>(&phi_s[pn2][pm4]) = o0;
      *reinterpret_cast<float4*>(&phi_s[pn2 + 1][pm4]) = o1;
    }
    __syncthreads();
    // GEMM2: out[n=tm+i][c=tn+j] += sum_m phi[n][m]*ktv[m][c]; d[n] += phi[n][m]*ksum[m]
    for (int m = 0; m < 32; m += 4) {
      float4 pa[4];
#pragma unroll
      for (int i = 0; i < 4; ++i) pa[i] = *reinterpret_cast<const float4*>(&phi_s[tm + i][m]);
      const float4 ks4 = *reinterpret_cast<const float4*>(&ksum_s[m]);
      const float ks[4] = {ks4.x, ks4.y, ks4.z, ks4.w};
#pragma unroll
      for (int mm = 0; mm < 4; ++mm) {
        const float4 kv = *reinterpret_cast<const float4*>(&ktv_s[m + mm][tn]);
#pragma unroll
        for (int i = 0; i < 4; ++i) {
          const float p = (&pa[i].x)[mm];
          oacc[i][0] = fmaf(p, kv.x, oacc[i][0]);
          oacc[i][1] = fmaf(p, kv.y, oacc[i][1]);
          oacc[i][2] = fmaf(p, kv.z, oacc[i][2]);
          oacc[i][3] = fmaf(p, kv.w, oacc[i][3]);
          dreg[i] = fmaf(p, ks[mm], dreg[i]);
        }
      }
    }
  }
  if ((t & 15) == 0) {
#pragma unroll
    for (int i = 0; i < 4; ++i) d_s[tm + i] = dreg[i] + EPS;
  }
  __syncthreads();
#pragma unroll
  for (int i = 0; i < 4; ++i) {
    const float dinv = 1.0f / d_s[tm + i];
    const float4 o = make_float4(oacc[i][0] * dinv, oacc[i][1] * dinv, oacc[i][2] * dinv,
                                 oacc[i][3] * dinv);
    *reinterpret_cast<float4*>(&attn[((size_t)(b * N + nb + tm + i)) * DIM + h * 64 + tn]) = o;
  }
}

}  // namespace

extern "C" void kernel_launch(void* const* d_in, const int* in_sizes, int n_in,
                              void* d_out, int out_size, void* d_ws, size_t ws_size,
                              hipStream_t stream) {
  const float* x = (const float*)d_in[0];      // (B,N,DIM)
  const float* w = (const float*)d_in[1];      // (H,C,M)
  const float* Wqkv = (const float*)d_in[2];   // (DIM, 3*DIM)
  const float* Wproj = (const float*)d_in[3];  // (DIM, DIM)
  const float* bproj = (const float*)d_in[4];  // (DIM,)
  float* out = (float*)d_out;

  float* qkv = (float*)d_ws;                          // 8192*2304
  float* ktv = qkv + (size_t)B * N * 3 * DIM;         // B*H*M*C
  float* ksum = ktv + (size_t)B * H * M * CD;         // B*H*M
  float* attn = ksum + (size_t)B * H * M;             // 8192*768

  // 1) qkv = x @ Wqkv
  sgemm_k<false><<<dim3(3 * DIM / 64, B * N / 64), 256, 0, stream>>>(
      x, Wqkv, nullptr, qkv, B * N, 3 * DIM, DIM);
  // 2) phi(k) -> ksum, ktv
  kv_stage_k<<<dim3(M / 64, H, B), 256, 0, stream>>>(qkv, w, ktv, ksum);
  // 3) phi(q) -> D, attn out (B,N,H*C)
  q_stage_k<<<dim3(N / 64, H, B), 256, 0, stream>>>(qkv, w, ktv, ksum, attn);
  // 4) out = attn @ Wproj + bproj
  sgemm_k<true><<<dim3(DIM / 64, B * N / 64), 256, 0, stream>>>(
      attn, Wproj, bproj, out, B * N, DIM, DIM);
}

// Round 2
// 236.278 us; speedup vs baseline: 3.9855x; 3.9855x over previous
//
#include <hip/hip_runtime.h>

typedef __attribute__((ext_vector_type(8))) short s16x8;
typedef __attribute__((ext_vector_type(4))) float f32x4;

#define MFMA(a, b, c) __builtin_amdgcn_mfma_f32_16x16x32_bf16(a, b, c, 0, 0, 0)

namespace {

constexpr int Bn = 4, Nn = 2048, Hn = 12, Mn = 384;
constexpr float SCALE = 0.35355339059327379f;   // 64^-0.25
constexpr float ISM = 0.05103103630798288f;     // 1/sqrt(384)
constexpr float EPS = 1e-8f;

__device__ inline unsigned short f2b(float f) {
  unsigned u = __builtin_bit_cast(unsigned, f);
  return (unsigned short)((u + 0x7fffu + ((u >> 16) & 1u)) >> 16);
}
__device__ inline float b2f(unsigned short h) {
  unsigned u = ((unsigned)h) << 16;
  return __builtin_bit_cast(float, u);
}

// ---------- conversion kernels ----------
__global__ __launch_bounds__(256) void cvt_x_k(const float* __restrict__ x,
                                               unsigned short* __restrict__ xb) {
  const int id = blockIdx.x * 256 + threadIdx.x;  // TOK*96 = 786432 threads
  const float* src = x + (size_t)id * 8;
  s16x8 o;
#pragma unroll
  for (int j = 0; j < 8; ++j) o[j] = (short)f2b(src[j]);
  *(s16x8*)(xb + (size_t)id * 8) = o;
}

// W (K=768 x Ndim) f32 -> wT (Ndim x 768) bf16
__global__ __launch_bounds__(256) void cvt_wT_k(const float* __restrict__ W,
                                                unsigned short* __restrict__ wT, int Ndim) {
  const int id = blockIdx.x * 256 + threadIdx.x;  // Ndim*96
  const int n = id / 96, kc = (id % 96) * 8;
  s16x8 o;
#pragma unroll
  for (int j = 0; j < 8; ++j) o[j] = (short)f2b(W[(size_t)(kc + j) * Ndim + n]);
  *(s16x8*)(wT + (size_t)n * 768 + kc) = o;
}

// w (H,64,384) f32 -> wt (H,384,64) bf16
__global__ __launch_bounds__(256) void cvt_wtr_k(const float* __restrict__ w,
                                                 unsigned short* __restrict__ wt) {
  const int id = blockIdx.x * 256 + threadIdx.x;  // 12*384*8 = 36864
  const int h = id / (384 * 8);
  const int r = id % (384 * 8);
  const int m = r / 8, cc = (r % 8) * 8;
  s16x8 o;
#pragma unroll
  for (int j = 0; j < 8; ++j) o[j] = (short)f2b(w[((size_t)h * 64 + cc + j) * 384 + m]);
  *(s16x8*)(wt + ((size_t)h * 384 + m) * 64 + cc) = o;
}

// ---------- 128x128 bf16 MFMA GEMM, A[M][768] @ Bt[N][768]^T ----------
template <bool BF16OUT>
__global__ __launch_bounds__(256) void gemm_bt_k(const unsigned short* __restrict__ A,
                                                 const unsigned short* __restrict__ Bt,
                                                 int Ktot, int ldOut,
                                                 unsigned short* __restrict__ obf,
                                                 float* __restrict__ of32,
                                                 const float* __restrict__ bias) {
  __shared__ unsigned short ldsA[128 * 64];
  __shared__ unsigned short ldsB[128 * 64];
  char* lA = (char*)ldsA;
  char* lB = (char*)ldsB;
  const int t = threadIdx.x, lane = t & 63, w = t >> 6;
  const int ln = lane & 15, kg = lane >> 4;
  const size_t bm = (size_t)blockIdx.y * 128, bn = (size_t)blockIdx.x * 128;
  const int wr = w >> 1, wc = w & 1;
  f32x4 acc[4][4];
#pragma unroll
  for (int i = 0; i < 4; ++i)
#pragma unroll
    for (int j = 0; j < 4; ++j) acc[i][j] = (f32x4){0.f, 0.f, 0.f, 0.f};

  const int srow = t >> 3, sslot = t & 7;
  for (int kb = 0; kb < Ktot; kb += 64) {
    s16x8 ra[4], rb[4];
#pragma unroll
    for (int j = 0; j < 4; ++j) {
      const int row = j * 32 + srow;
      ra[j] = *(const s16x8*)(A + (bm + row) * 768 + kb + sslot * 8);
      rb[j] = *(const s16x8*)(Bt + (bn + row) * 768 + kb + sslot * 8);
    }
    __syncthreads();
#pragma unroll
    for (int j = 0; j < 4; ++j) {
      const int row = j * 32 + srow;
      const int byt = row * 128 + ((sslot ^ (row & 7)) << 4);
      *(s16x8*)(lA + byt) = ra[j];
      *(s16x8*)(lB + byt) = rb[j];
    }
    __syncthreads();
#pragma unroll
    for (int ks = 0; ks < 2; ++ks) {
      s16x8 af[4], bfr[4];
#pragma unroll
      for (int mi = 0; mi < 4; ++mi) {
        const int row = wr * 64 + mi * 16 + ln;
        af[mi] = *(const s16x8*)(lA + row * 128 + (((ks * 4 + kg) ^ (row & 7)) << 4));
      }
#pragma unroll
      for (int ni = 0; ni < 4; ++ni) {
        const int row = wc * 64 + ni * 16 + ln;
        bfr[ni] = *(const s16x8*)(lB + row * 128 + (((ks * 4 + kg) ^ (row & 7)) << 4));
      }
#pragma unroll
      for (int mi = 0; mi < 4; ++mi)
#pragma unroll
        for (int ni = 0; ni < 4; ++ni) acc[mi][ni] = MFMA(af[mi], bfr[ni], acc[mi][ni]);
    }
  }
#pragma unroll
  for (int mi = 0; mi < 4; ++mi)
#pragma unroll
    for (int ni = 0; ni < 4; ++ni) {
      const size_t orow0 = bm + wr * 64 + mi * 16 + kg * 4;
      const size_t ocol = bn + wc * 64 + ni * 16 + ln;
#pragma unroll
      for (int r = 0; r < 4; ++r) {
        const float v = acc[mi][ni][r];
        if (BF16OUT)
          obf[(orow0 + r) * ldOut + ocol] = f2b(v);
        else
          of32[(orow0 + r) * ldOut + ocol] = v + bias[ocol];
      }
    }
}

// ---------- stage 2: phi(k) -> ktv partials + ksum partials ----------
// grid (8 = 4 n-groups x 2 m-halves, H, B), 512 threads
__global__ __launch_bounds__(512) void stage2_k(const unsigned short* __restrict__ qkv,
                                                const unsigned short* __restrict__ wt,
                                                float* __restrict__ ktv_part,
                                                float* __restrict__ ksum_part) {
  __shared__ unsigned short kfT[192 * 64];  // [m_local][n] swizzled, pitch 128B
  __shared__ unsigned short vt[64 * 64];    // [c][n] swizzled, pitch 128B
  __shared__ float sqh[64];
  char* kfT_b = (char*)kfT;
  char* vt_b = (char*)vt;
  const int t = threadIdx.x, lane = t & 63, w = t >> 6;
  const int ln = lane & 15, kg = lane >> 4;
  const int gx = blockIdx.x, h = blockIdx.y, b = blockIdx.z;
  const int ng = gx >> 1, mh = gx & 1, m0 = mh * 192;
  const int bh = b * Hn + h;
  const int ntile = w & 3, mgrp = w >> 2;          // GEMM1 assignment
  const int mts = (w & 3) * 3, cts = (w >> 2) * 2; // GEMM2 assignment
  f32x4 acc[3][2];
#pragma unroll
  for (int j = 0; j < 3; ++j)
#pragma unroll
    for (int i = 0; i < 2; ++i) acc[j][i] = (f32x4){0.f, 0.f, 0.f, 0.f};
  float ksr = 0.f;

  for (int ch = 0; ch < 8; ++ch) {
    const int nbase = ng * 512 + ch * 64;
    __syncthreads();
    {  // stage v (transposed) + sq-half partials
      const int n = t >> 3, c0 = (t & 7) * 8;
      const size_t tok = (size_t)b * Nn + nbase + n;
      const s16x8 vv = *(const s16x8*)(qkv + tok * 2304 + 1536 + h * 64 + c0);
#pragma unroll
      for (int j = 0; j < 8; ++j) {
        const int c = c0 + j;
        *(unsigned short*)(vt_b + c * 128 + ((2 * n) ^ ((c & 7) << 4))) = (unsigned short)vv[j];
      }
      const s16x8 kk = *(const s16x8*)(qkv + tok * 2304 + 768 + h * 64 + c0);
      float s = 0.f;
#pragma unroll
      for (int j = 0; j < 8; ++j) {
        const float f = b2f((unsigned short)kk[j]);
        s = fmaf(f, f, s);
      }
      s += __shfl_xor(s, 1);
      s += __shfl_xor(s, 2);
      s += __shfl_xor(s, 4);
      if ((t & 7) == 0) sqh[n] = 0.5f * SCALE * SCALE * s;
    }
    __syncthreads();
    {  // GEMM1: proj -> exp -> kfT (bf16, swizzled)
      const size_t tokr = (size_t)b * Nn + nbase + ntile * 16 + ln;
      const unsigned short* ap = qkv + tokr * 2304 + 768 + h * 64 + kg * 8;
      const s16x8 a0 = *(const s16x8*)ap;
      const s16x8 a1 = *(const s16x8*)(ap + 32);
      const int nr = ntile * 16 + kg * 4;
      const float s0 = sqh[nr], s1 = sqh[nr + 1], s2 = sqh[nr + 2], s3 = sqh[nr + 3];
#pragma unroll
      for (int i = 0; i < 6; ++i) {
        const int mloc = (mgrp * 6 + i) * 16 + ln;
        const unsigned short* bp = wt + ((size_t)h * 384 + m0 + mloc) * 64 + kg * 8;
        f32x4 p = (f32x4){0.f, 0.f, 0.f, 0.f};
        p = MFMA(a0, *(const s16x8*)bp, p);
        p = MFMA(a1, *(const s16x8*)(bp + 32), p);
        const float e0 = __expf(fmaf(SCALE, p[0], -s0)) * ISM;
        const float e1 = __expf(fmaf(SCALE, p[1], -s1)) * ISM;
        const float e2 = __expf(fmaf(SCALE, p[2], -s2)) * ISM;
        const float e3 = __expf(fmaf(SCALE, p[3], -s3)) * ISM;
        uint2 pk;
        pk.x = (unsigned)f2b(e0) | ((unsigned)f2b(e1) << 16);
        pk.y = (unsigned)f2b(e2) | ((unsigned)f2b(e3) << 16);
        const int bytn = 32 * ntile + 8 * kg;  // = nr*2
        *(uint2*)(kfT_b + mloc * 128 + (bytn ^ ((mloc & 7) << 4))) = pk;
      }
    }
    __syncthreads();
    if (t < 192) {  // ksum partial (waves 0-2)
#pragma unroll
      for (int s8 = 0; s8 < 8; ++s8) {
        const s16x8 v = *(const s16x8*)(kfT_b + t * 128 + ((s8 * 16) ^ ((t & 7) << 4)));
#pragma unroll
        for (int j = 0; j < 8; ++j) ksr += b2f((unsigned short)v[j]);
      }
    }
    // GEMM2: ktv += kfT @ v
#pragma unroll
    for (int half = 0; half < 2; ++half) {
      s16x8 a[3], bb[2];
#pragma unroll
      for (int j = 0; j < 3; ++j) {
        const int m = (mts + j) * 16 + ln;
        a[j] = *(const s16x8*)(kfT_b + m * 128 + ((half * 64 + kg * 16) ^ ((m & 7) << 4)));
      }
#pragma unroll
      for (int i = 0; i < 2; ++i) {
        const int c = (cts + i) * 16 + ln;
        bb[i] = *(const s16x8*)(vt_b + c * 128 + ((half * 64 + kg * 16) ^ ((c & 7) << 4)));
      }
#pragma unroll
      for (int j = 0; j < 3; ++j)
#pragma unroll
        for (int i = 0; i < 2; ++i) acc[j][i] = MFMA(a[j], bb[i], acc[j][i]);
    }
  }
  // write partials
  float* base = ktv_part + ((size_t)ng * 48 + bh) * (384 * 64);
#pragma unroll
  for (int j = 0; j < 3; ++j)
#pragma unroll
    for (int i = 0; i < 2; ++i) {
      const int mrow0 = m0 + (mts + j) * 16 + kg * 4;
      const int c = (cts + i) * 16 + ln;
#pragma unroll
      for (int r = 0; r < 4; ++r) base[(size_t)(mrow0 + r) * 64 + c] = acc[j][i][r];
    }
  if (t < 192) ksum_part[((size_t)ng * 48 + bh) * 384 + m0 + t] = ksr;
}

// ---------- reductions over the 4 n-groups ----------
__global__ __launch_bounds__(256) void reduce_ktv_k(const float* __restrict__ part,
                                                    unsigned short* __restrict__ ktvt) {
  const int bid = blockIdx.x;
  const int bh = bid / 96, chunk = bid % 96;
  const int idx = chunk * 256 + threadIdx.x;  // 0..24575
  const int m = idx >> 6, c = idx & 63;
  const size_t o = (size_t)bh * 24576 + idx;
  const size_t gs = (size_t)48 * 24576;
  const float s = part[o] + part[o + gs] + part[o + 2 * gs] + part[o + 3 * gs];
  ktvt[((size_t)bh * 64 + c) * 384 + m] = f2b(s);  // transposed [bh][c][m]
}
__global__ __launch_bounds__(256) void reduce_ksum_k(const float* __restrict__ partk,
                                                     float* __restrict__ ksum) {
  const int idx = blockIdx.x * 256 + threadIdx.x;  // 48*384
  const int gs = 48 * 384;
  ksum[idx] = partk[idx] + partk[idx + gs] + partk[idx + 2 * gs] + partk[idx + 3 * gs];
}

// ---------- stage 3: phi(q) -> out/D -> attn ----------
// grid (32, H, B), 512 threads
__global__ __launch_bounds__(512) void stage3_k(const unsigned short* __restrict__ qkv,
                                                const unsigned short* __restrict__ wt,
                                                const unsigned short* __restrict__ ktvt,
                                                const float* __restrict__ ksum,
                                                unsigned short* __restrict__ attn) {
  __shared__ unsigned short qf[64 * 392];  // [n][m], pitch 784B (f32-free bank spread)
  __shared__ float sqh[64];
  __shared__ float ds[64];
  char* qf_b = (char*)qf;
  const int t = threadIdx.x, lane = t & 63, w = t >> 6;
  const int ln = lane & 15, kg = lane >> 4;
  const int nb = blockIdx.x, h = blockIdx.y, b = blockIdx.z, bh = b * Hn + h;
  const size_t tok0 = (size_t)b * Nn + nb * 64;

  {  // sq-half
    const int n = t >> 3, c0 = (t & 7) * 8;
    const s16x8 qq = *(const s16x8*)(qkv + (tok0 + n) * 2304 + h * 64 + c0);
    float s = 0.f;
#pragma unroll
    for (int j = 0; j < 8; ++j) {
      const float f = b2f((unsigned short)qq[j]);
      s = fmaf(f, f, s);
    }
    s += __shfl_xor(s, 1);
    s += __shfl_xor(s, 2);
    s += __shfl_xor(s, 4);
    if ((t & 7) == 0) sqh[n] = 0.5f * SCALE * SCALE * s;
  }
  __syncthreads();
  {  // GEMM1: proj q -> exp -> qf LDS
    const int ntile = w & 3, mg = w >> 2;
    const size_t tokr = tok0 + ntile * 16 + ln;
    const unsigned short* ap = qkv + tokr * 2304 + h * 64 + kg * 8;
    const s16x8 a0 = *(const s16x8*)ap;
    const s16x8 a1 = *(const s16x8*)(ap + 32);
    const int nr = ntile * 16 + kg * 4;
    const float s0 = sqh[nr], s1 = sqh[nr + 1], s2 = sqh[nr + 2], s3 = sqh[nr + 3];
#pragma unroll
    for (int i = 0; i < 12; ++i) {
      const int m = (mg * 12 + i) * 16 + ln;
      const unsigned short* bp = wt + ((size_t)h * 384 + m) * 64 + kg * 8;
      f32x4 p = (f32x4){0.f, 0.f, 0.f, 0.f};
      p = MFMA(a0, *(const s16x8*)bp, p);
      p = MFMA(a1, *(const s16x8*)(bp + 32), p);
      *(unsigned short*)(qf_b + (nr + 0) * 784 + m * 2) = f2b(__expf(fmaf(SCALE, p[0], -s0)) * ISM);
      *(unsigned short*)(qf_b + (nr + 1) * 784 + m * 2) = f2b(__expf(fmaf(SCALE, p[1], -s1)) * ISM);
      *(unsigned short*)(qf_b + (nr + 2) * 784 + m * 2) = f2b(__expf(fmaf(SCALE, p[2], -s2)) * ISM);
      *(unsigned short*)(qf_b + (nr + 3) * 784 + m * 2) = f2b(__expf(fmaf(SCALE, p[3], -s3)) * ISM);
    }
  }
  __syncthreads();
  {  // D reduction: D_n = sum_m qf[n][m]*ksum[m] + EPS
    const int n = t >> 3, j8 = t & 7;
    const float* ks = ksum + (size_t)bh * 384 + j8 * 48;
    float s = 0.f;
    for (int j = 0; j < 48; ++j)
      s = fmaf(b2f(*(const unsigned short*)(qf_b + n * 784 + (j8 * 48 + j) * 2)), ks[j], s);
    s += __shfl_xor(s, 1);
    s += __shfl_xor(s, 2);
    s += __shfl_xor(s, 4);
    if (j8 == 0) ds[n] = s + EPS;
  }
  // GEMM2: out = qf @ ktvt^T
  const int ntile = w & 3, c0t = (w >> 2) * 2;
  f32x4 acc[2];
  acc[0] = (f32x4){0.f, 0.f, 0.f, 0.f};
  acc[1] = (f32x4){0.f, 0.f, 0.f, 0.f};
  const int n = ntile * 16 + ln;
#pragma unroll
  for (int ms = 0; ms < 12; ++ms) {
    const s16x8 a = *(const s16x8*)(qf_b + n * 784 + ms * 64 + kg * 16);
#pragma unroll
    for (int i = 0; i < 2; ++i) {
      const int c = (c0t + i) * 16 + ln;
      const s16x8 bb = *(const s16x8*)(ktvt + ((size_t)bh * 64 + c) * 384 + ms * 32 + kg * 8);
      acc[i] = MFMA(a, bb, acc[i]);
    }
  }
  __syncthreads();
#pragma unroll
  for (int i = 0; i < 2; ++i) {
    const int c = (c0t + i) * 16 + ln;
    const int nr = ntile * 16 + kg * 4;
#pragma unroll
    for (int r = 0; r < 4; ++r) {
      const float v = acc[i][r] / ds[nr + r];
      attn[(tok0 + nr + r) * 768 + h * 64 + c] = f2b(v);
    }
  }
}

}  // namespace

extern "C" void kernel_launch(void* const* d_in, const int* in_sizes, int n_in,
                              void* d_out, int out_size, void* d_ws, size_t ws_size,
                              hipStream_t stream) {
  const float* x = (const float*)d_in[0];
  const float* w = (const float*)d_in[1];
  const float* Wqkv = (const float*)d_in[2];
  const float* Wproj = (const float*)d_in[3];
  const float* bproj = (const float*)d_in[4];

  char* ws = (char*)d_ws;
  // region0 (aliased): [xb 12,582,912 | wqT 3,538,944]  vs  [ktv_part 18,874,368 | ksum_part 294,912]
  unsigned short* xb = (unsigned short*)(ws);
  unsigned short* wqT = (unsigned short*)(ws + 12582912);
  float* ktv_part = (float*)(ws);
  float* ksum_part = (float*)(ws + 18874368);
  char* p = ws + 19169280;
  unsigned short* qkvb = (unsigned short*)p;  p += 37748736;   // (8192,2304) bf16
  unsigned short* wt = (unsigned short*)p;    p += 589824;     // (12,384,64) bf16
  unsigned short* ktvt = (unsigned short*)p;  p += 2359296;    // (48,64,384) bf16
  float* ksum = (float*)p;                    p += 73728;      // (48,384) f32
  unsigned short* attn = (unsigned short*)p;  p += 12582912;   // (8192,768) bf16
  unsigned short* wpT = (unsigned short*)p;                    // (768,768) bf16

  cvt_x_k<<<3072, 256, 0, stream>>>(x, xb);
  cvt_wT_k<<<864, 256, 0, stream>>>(Wqkv, wqT, 2304);
  cvt_wT_k<<<288, 256, 0, stream>>>(Wproj, wpT, 768);
  cvt_wtr_k<<<144, 256, 0, stream>>>(w, wt);
  gemm_bt_k<true><<<dim3(18, 64), 256, 0, stream>>>(xb, wqT, 768, 2304, qkvb, nullptr, nullptr);
  stage2_k<<<dim3(8, 12, 4), 512, 0, stream>>>(qkvb, wt, ktv_part, ksum_part);
  reduce_ktv_k<<<4608, 256, 0, stream>>>(ktv_part, ktvt);
  reduce_ksum_k<<<72, 256, 0, stream>>>(ksum_part, ksum);
  stage3_k<<<dim3(32, 12, 4), 512, 0, stream>>>(qkvb, wt, ktvt, ksum, attn);
  gemm_bt_k<false><<<dim3(6, 64), 256, 0, stream>>>(attn, wpT, 768, 768, nullptr,
                                                    (float*)d_out, bproj);
}